// Round 13
// baseline (181.876 us; speedup 1.0000x reference)
//
#include <hip/hip_runtime.h>

#define BATCH 16384
#define KDIM  8192
#define ODIM  32
#define SK    8                   // split-K across blocks (grid 2048 -> 8 blocks/CU)
#define KSLICE (KDIM / SK)        // 1024 k per block
#define NWAVE 4
#define THREADS (NWAVE * 64)
#define KT    32                  // k per LDS tile
#define NTILE (KSLICE / KT)       // 32 tiles
#define LP    36                  // padded row stride (floats): 16B-aligned, uniform banks

// ---------------------------------------------------------------------------
// Prep: bwT[k][o] = sign(w[o][k]) as +-1.0f/0, + per-block partial sum |w|
// ---------------------------------------------------------------------------
__global__ void prep_kernel(const float* __restrict__ w,
                            float* __restrict__ bwT,
                            float* __restrict__ partial) {
    int idx = blockIdx.x * 256 + threadIdx.x;     // coalesced over 32*8192
    int o = idx >> 13;
    int k = idx & (KDIM - 1);
    float v = w[idx];
    float s = (v > 0.f) ? 1.f : ((v < 0.f) ? -1.f : 0.f);
    bwT[(size_t)k * ODIM + o] = s;

    float a = fabsf(v);
    #pragma unroll
    for (int off = 32; off; off >>= 1) a += __shfl_down(a, off, 64);
    __shared__ float red[4];
    int lane = threadIdx.x & 63, wv = threadIdx.x >> 6;
    if (lane == 0) red[wv] = a;
    __syncthreads();
    if (threadIdx.x == 0)
        partial[blockIdx.x] = (red[0] + red[1]) + (red[2] + red[3]);
}

// ---------------------------------------------------------------------------
// Main: 2048 blocks x 256 thr = 8 blocks/CU (32 waves/CU). Tile = 64 rows x
// 32 k, double-buffered padded LDS. CRITICAL ORDER per tile: issue next-tile
// loads -> barrier -> ds_read -> 256 FMAs (covers the in-flight load latency)
// -> ds_write next tile (vmcnt satisfied by then) -> next barrier.
// (R7-R10 wrote BEFORE the FMAs: exposed ~500cyc vmcnt stall every tile.)
// lane = row -> weights wave-uniform (readfirstlane) -> scalar s_load.
// kb = bid&7: each of 8 XCDs owns one 128KB weight slice (L2-resident).
// Split-K=8 partials, no atomics, deterministic.
// ---------------------------------------------------------------------------
__global__ __launch_bounds__(THREADS, 8)
void main_kernel(const float* __restrict__ x,
                 const float* __restrict__ bwT,
                 float* __restrict__ pout) {
    __shared__ union {
        float buf[2][64][LP];     // 18432 B
        float part[2][ODIM][65];  // 16640 B
    } sm;

    const int tid  = threadIdx.x;
    const int wv   = __builtin_amdgcn_readfirstlane(tid >> 6);  // MUST be SGPR
    const int lane = tid & 63;
    const int kb   = blockIdx.x & 7;           // XCD-locked weight slice
    const int rb   = blockIdx.x >> 3;          // 0..255
    const size_t rowbase = (size_t)rb * 64;
    const int kbase = kb * KSLICE;

    // staging: thread t writes float4 at (row = t>>3, q = t&7) and (+32 rows)
    const int sr = tid >> 3;
    const int sq = tid & 7;
    const float* __restrict__ xg0 = x + (rowbase + sr) * (size_t)KDIM + kbase + 4 * sq;
    const float* __restrict__ xg1 = xg0 + (size_t)32 * KDIM;

    float acc[ODIM];
    #pragma unroll
    for (int o = 0; o < ODIM; ++o) acc[o] = 0.f;

    // prologue: tile 0 -> buf0
    float4 v0 = *(const float4*)xg0;
    float4 v1 = *(const float4*)xg1;
    *(float4*)&sm.buf[0][sr][4 * sq]      = v0;
    *(float4*)&sm.buf[0][sr + 32][4 * sq] = v1;

    const float* __restrict__ wb = bwT + (size_t)(kbase + wv * 8) * ODIM;

    for (int t = 0; t < NTILE; ++t) {
        float4 n0, n1;
        if (t + 1 < NTILE) {
            n0 = *(const float4*)(xg0 + (t + 1) * KT);   // in flight during FMAs
            n1 = *(const float4*)(xg1 + (t + 1) * KT);
        }

        __syncthreads();   // buf[t&1] fully written; all t-1 reads retired

        // this wave's 8 k's of the tile: two structural-floor ds_read_b128
        const float4 xk0 = *(const float4*)&sm.buf[t & 1][lane][wv * 8];
        const float4 xk1 = *(const float4*)&sm.buf[t & 1][lane][wv * 8 + 4];

        const float xs[8] = {xk0.x, xk0.y, xk0.z, xk0.w,
                             xk1.x, xk1.y, xk1.z, xk1.w};
        const float* __restrict__ wt = wb + (size_t)t * KT * ODIM;
        #pragma unroll
        for (int kk = 0; kk < 8; ++kk) {
            const float* __restrict__ wo = wt + kk * ODIM;   // wave-uniform
            #pragma unroll
            for (int o = 0; o < ODIM; ++o)
                acc[o] = fmaf(xs[kk], wo[o], acc[o]);
        }

        // write AFTER the FMA block: load latency already covered by compute
        if (t + 1 < NTILE) {
            *(float4*)&sm.buf[(t + 1) & 1][sr][4 * sq]      = n0;
            *(float4*)&sm.buf[(t + 1) & 1][sr + 32][4 * sq] = n1;
        }
    }

    // two-phase cross-wave reduce (fits union)
    __syncthreads();
    if (wv < 2) {
        #pragma unroll
        for (int o = 0; o < ODIM; ++o) sm.part[wv][o][lane] = acc[o];
    }
    __syncthreads();
    if (wv >= 2) {
        #pragma unroll
        for (int o = 0; o < ODIM; ++o) sm.part[wv - 2][o][lane] += acc[o];
    }
    __syncthreads();

    float* __restrict__ pb = pout + ((size_t)kb * BATCH + rowbase) * ODIM;
    #pragma unroll
    for (int i = 0; i < 8; ++i) {
        int j = tid + THREADS * i;        // j = r*32 + o, fully coalesced
        int r = j >> 5, o = j & 31;
        pb[j] = sm.part[0][o][r] + sm.part[1][o][r];
    }
}

// ---------------------------------------------------------------------------
// Final: recompute scale from the 1024 |w| partials (L2-hot, deterministic),
// then out = (sum of 8 split-K partials) * scale. Grid 512 x 256.
// ---------------------------------------------------------------------------
__global__ void reduce_kernel(const float* __restrict__ pout,
                              const float* __restrict__ partial,
                              float* __restrict__ out) {
    const int t = threadIdx.x;
    float a = (partial[t] + partial[t + 256]) + (partial[t + 512] + partial[t + 768]);
    #pragma unroll
    for (int off = 32; off; off >>= 1) a += __shfl_down(a, off, 64);
    __shared__ float red[4];
    __shared__ float sbc;
    if ((t & 63) == 0) red[t >> 6] = a;
    __syncthreads();
    if (t == 0)
        sbc = ((red[0] + red[1]) + (red[2] + red[3])) / (float)(ODIM * KDIM);
    __syncthreads();
    const float s = sbc;

    const int STRIDE = BATCH * ODIM / 4;          // float4 per split slice
    int i = blockIdx.x * 256 + t;
    const float4* p = (const float4*)pout;
    float4 r = p[i];
    #pragma unroll
    for (int k = 1; k < SK; ++k) {
        float4 A = p[i + k * STRIDE];
        r.x += A.x; r.y += A.y; r.z += A.z; r.w += A.w;
    }
    r.x *= s; r.y *= s; r.z *= s; r.w *= s;
    ((float4*)out)[i] = r;
}

// ---------------------------------------------------------------------------
extern "C" void kernel_launch(void* const* d_in, const int* in_sizes, int n_in,
                              void* d_out, int out_size, void* d_ws, size_t ws_size,
                              hipStream_t stream) {
    const float* x = (const float*)d_in[0];
    const float* w = (const float*)d_in[1];
    float* out = (float*)d_out;

    float* wsf     = (float*)d_ws;
    float* partial = wsf;                       // 1024 floats
    float* bwT     = wsf + 1024;                // 262144 floats (1 MiB), [k][o]
    float* pout    = wsf + 1024 + ODIM * KDIM;  // SK * 524288 floats (16 MiB)

    prep_kernel<<<1024, 256, 0, stream>>>(w, bwT, partial);
    main_kernel<<<256 * SK, THREADS, 0, stream>>>(x, bwT, pout);
    reduce_kernel<<<BATCH * ODIM / 4 / 256, 256, 0, stream>>>(pout, partial, out);
}

// Round 14
// 142.848 us; speedup vs baseline: 1.2732x; 1.2732x over previous
//
#include <hip/hip_runtime.h>

#define BATCH 16384
#define KDIM  8192
#define ODIM  32
#define SK    8                   // split-K across blocks
#define KSLICE (KDIM / SK)        // 1024 k per block
#define NWAVE 4
#define THREADS (NWAVE * 64)
#define KT    32                  // k per LDS tile
#define NTILE (KSLICE / KT)       // 32 tiles
#define LP    36                  // padded x row stride (floats)

typedef short bf16x8 __attribute__((ext_vector_type(8)));
typedef float f32x16 __attribute__((ext_vector_type(16)));

// ---------------------------------------------------------------------------
// Prep: bwTo[o][k] = sign(w[o][k]) as bf16 (+-1.0 exact / 0), + |w| partials
// ---------------------------------------------------------------------------
__global__ void prep_kernel(const float* __restrict__ w,
                            unsigned short* __restrict__ bwTo,
                            float* __restrict__ partial) {
    int idx = blockIdx.x * 256 + threadIdx.x;     // = o*8192 + k, coalesced
    float v = w[idx];
    bwTo[idx] = (v > 0.f) ? 0x3F80u : ((v < 0.f) ? 0xBF80u : 0u);

    float a = fabsf(v);
    #pragma unroll
    for (int off = 32; off; off >>= 1) a += __shfl_down(a, off, 64);
    __shared__ float red[4];
    int lane = threadIdx.x & 63, wv = threadIdx.x >> 6;
    if (lane == 0) red[wv] = a;
    __syncthreads();
    if (threadIdx.x == 0)
        partial[blockIdx.x] = (red[0] + red[1]) + (red[2] + red[3]);
}

// ---------------------------------------------------------------------------
// Main: same staging skeleton as R10 (proven), compute swapped to MFMA.
// Wave wv: kH=wv&1 (k 16*kH..+15 of tile), rH=wv>>1 (rows 32*rH..+31).
// A-frag: lane l holds 8 consecutive k (k-group l>>5) of row (l&31)+32*rH,
//         split x = hi_bf16 + lo_bf16 (exact bit ops) -> 2 MFMA into f32x16.
// B-frag: lane l holds 8 consecutive k of weight row o=l&31 from bf16 table
//         (64KB per kb slice, L2-resident; kb=bid&7 XCD-locked).
// C/D (m74/m101-verified): o=lane&31, row=(reg&3)+8*(reg>>2)+4*(lane>>5).
// k-sub-layout identical for A and B -> any k permutation cancels in the sum.
// ---------------------------------------------------------------------------
__global__ __launch_bounds__(THREADS, 6)
void main_kernel(const float* __restrict__ x,
                 const unsigned short* __restrict__ bwTo,
                 float* __restrict__ pout) {
    __shared__ union {
        float buf[2][64][LP];     // 18432 B
        float part[2][64][33];    // 16896 B
    } sm;

    const int tid  = threadIdx.x;
    const int wv   = __builtin_amdgcn_readfirstlane(tid >> 6);
    const int lane = tid & 63;
    const int l31  = lane & 31;
    const int lhi  = lane >> 5;
    const int kH   = wv & 1;
    const int rH   = wv >> 1;
    const int kb   = blockIdx.x & 7;           // XCD-locked weight slice
    const int rb   = blockIdx.x >> 3;          // 0..255
    const size_t rowbase = (size_t)rb * 64;
    const int kbase = kb * KSLICE;

    // x staging: thread t -> float4 at (row = t>>3, q = t&7) and (+32 rows)
    const int sr = tid >> 3;
    const int sq = tid & 7;
    const float* __restrict__ xg0 = x + (rowbase + sr) * (size_t)KDIM + kbase + 4 * sq;
    const float* __restrict__ xg1 = xg0 + (size_t)32 * KDIM;

    // B-frag pointer: 8 consecutive bf16 of weight row o=l31
    const unsigned short* __restrict__ bp =
        bwTo + (size_t)l31 * KDIM + kbase + kH * 16 + lhi * 8;

    f32x16 acc;
    #pragma unroll
    for (int i = 0; i < 16; ++i) acc[i] = 0.f;

    // prologue: tile 0 -> buf0; B(0) in flight
    float4 v0 = *(const float4*)xg0;
    float4 v1 = *(const float4*)xg1;
    bf16x8 bcur = *(const bf16x8*)bp;
    *(float4*)&sm.buf[0][sr][4 * sq]      = v0;
    *(float4*)&sm.buf[0][sr + 32][4 * sq] = v1;

    const int xrow = rH * 32 + l31;            // this lane's A row in the tile
    const int koff = kH * 16 + lhi * 8;        // this lane's k offset (floats)

    for (int t = 0; t < NTILE; ++t) {
        float4 n0, n1;
        bf16x8 bnext;
        if (t + 1 < NTILE) {
            n0 = *(const float4*)(xg0 + (t + 1) * KT);       // in flight over MFMA phase
            n1 = *(const float4*)(xg1 + (t + 1) * KT);
            bnext = *(const bf16x8*)(bp + (t + 1) * KT);
        }

        __syncthreads();   // buf[t&1] ready; buf[(t+1)&1] free

        // A: 8 consecutive fp32 of one row -> split to hi/lo bf16 (exact bits)
        const float4 xa = *(const float4*)&sm.buf[t & 1][xrow][koff];
        const float4 xb = *(const float4*)&sm.buf[t & 1][xrow][koff + 4];
        const float xf[8] = {xa.x, xa.y, xa.z, xa.w, xb.x, xb.y, xb.z, xb.w};
        bf16x8 ahi, alo;
        #pragma unroll
        for (int j = 0; j < 8; ++j) {
            unsigned b = __float_as_uint(xf[j]);
            float lo = xf[j] - __uint_as_float(b & 0xFFFF0000u);   // exact
            ahi[j] = (short)(b >> 16);
            alo[j] = (short)(__float_as_uint(lo) >> 16);
        }

        acc = __builtin_amdgcn_mfma_f32_32x32x16_bf16(ahi, bcur, acc, 0, 0, 0);
        acc = __builtin_amdgcn_mfma_f32_32x32x16_bf16(alo, bcur, acc, 0, 0, 0);

        if (t + 1 < NTILE) {
            *(float4*)&sm.buf[(t + 1) & 1][sr][4 * sq]      = n0;
            *(float4*)&sm.buf[(t + 1) & 1][sr + 32][4 * sq] = n1;
            bcur = bnext;
        }
    }

    // scatter acc to LDS (C/D layout), combine k-halves, coalesced store
    __syncthreads();
    #pragma unroll
    for (int r = 0; r < 16; ++r) {
        int row32 = (r & 3) + 8 * (r >> 2) + 4 * lhi;
        sm.part[kH][rH * 32 + row32][l31] = acc[r];
    }
    __syncthreads();

    float* __restrict__ pb = pout + ((size_t)kb * BATCH + rowbase) * ODIM;
    #pragma unroll
    for (int i = 0; i < 8; ++i) {
        int j = tid + THREADS * i;        // j = r*32 + o, coalesced
        int r = j >> 5, o = j & 31;
        pb[j] = sm.part[0][r][o] + sm.part[1][r][o];
    }
}

// ---------------------------------------------------------------------------
// Final: recompute scale from |w| partials (deterministic), sum SK partials
// ---------------------------------------------------------------------------
__global__ void reduce_kernel(const float* __restrict__ pout,
                              const float* __restrict__ partial,
                              float* __restrict__ out) {
    const int t = threadIdx.x;
    float a = (partial[t] + partial[t + 256]) + (partial[t + 512] + partial[t + 768]);
    #pragma unroll
    for (int off = 32; off; off >>= 1) a += __shfl_down(a, off, 64);
    __shared__ float red[4];
    __shared__ float sbc;
    if ((t & 63) == 0) red[t >> 6] = a;
    __syncthreads();
    if (t == 0)
        sbc = ((red[0] + red[1]) + (red[2] + red[3])) / (float)(ODIM * KDIM);
    __syncthreads();
    const float s = sbc;

    const int STRIDE = BATCH * ODIM / 4;
    int i = blockIdx.x * 256 + t;
    const float4* p = (const float4*)pout;
    float4 r = p[i];
    #pragma unroll
    for (int k = 1; k < SK; ++k) {
        float4 A = p[i + k * STRIDE];
        r.x += A.x; r.y += A.y; r.z += A.z; r.w += A.w;
    }
    r.x *= s; r.y *= s; r.z *= s; r.w *= s;
    ((float4*)out)[i] = r;
}

// ---------------------------------------------------------------------------
extern "C" void kernel_launch(void* const* d_in, const int* in_sizes, int n_in,
                              void* d_out, int out_size, void* d_ws, size_t ws_size,
                              hipStream_t stream) {
    const float* x = (const float*)d_in[0];
    const float* w = (const float*)d_in[1];
    float* out = (float*)d_out;

    float* wsf = (float*)d_ws;
    float* partial        = wsf;                       // 1024 floats
    unsigned short* bwTo  = (unsigned short*)(wsf + 1024);   // 32*8192 bf16 = 512 KB
    float* pout           = wsf + 1024 + (ODIM * KDIM / 2);  // SK*524288 floats (16 MB)

    prep_kernel<<<1024, 256, 0, stream>>>(w, bwTo, partial);
    main_kernel<<<256 * SK, THREADS, 0, stream>>>(x, bwTo, pout);
    reduce_kernel<<<BATCH * ODIM / 4 / 256, 256, 0, stream>>>(pout, partial, out);
}

// Round 17
// 142.055 us; speedup vs baseline: 1.2803x; 1.0056x over previous
//
#include <hip/hip_runtime.h>

#define BATCH 16384
#define KDIM  8192
#define ODIM  32
#define SK    8
#define KSLICE (KDIM / SK)       // 1024 k per block
#define KT    32                 // k per tile
#define NTILE (KSLICE / KT)      // 32 tiles
#define THREADS 256

typedef short bf16x8 __attribute__((ext_vector_type(8)));
typedef float f32x16 __attribute__((ext_vector_type(16)));

__device__ __forceinline__ void gload16(const float* g, void* l) {
    __builtin_amdgcn_global_load_lds(
        (const __attribute__((address_space(1))) void*)g,
        (__attribute__((address_space(3))) void*)l, 16, 0, 0);
}

// ---------------------------------------------------------------------------
// Prep: bwTo[o][k] = sign(w[o][k]) as bf16 (+-1.0 exact / 0), + |w| partials
// ---------------------------------------------------------------------------
__global__ void prep_kernel(const float* __restrict__ w,
                            unsigned short* __restrict__ bwTo,
                            float* __restrict__ partial) {
    int idx = blockIdx.x * 256 + threadIdx.x;     // = o*8192 + k, coalesced
    float v = w[idx];
    bwTo[idx] = (v > 0.f) ? 0x3F80u : ((v < 0.f) ? 0xBF80u : 0u);

    float a = fabsf(v);
    #pragma unroll
    for (int off = 32; off; off >>= 1) a += __shfl_down(a, off, 64);
    __shared__ float red[4];
    int lane = threadIdx.x & 63, wv = threadIdx.x >> 6;
    if (lane == 0) red[wv] = a;
    __syncthreads();
    if (threadIdx.x == 0)
        partial[blockIdx.x] = (red[0] + red[1]) + (red[2] + red[3]);
}

// ---------------------------------------------------------------------------
// Main: R14's barrier-per-tile structure with global_load_lds direct staging.
// Correctness is ORDER-IMMUNE: __syncthreads' implicit vmcnt(0) drain before
// s_barrier retires ALL of a wave's outstanding VMEM (no counted-vmcnt
// accounting — the R15/R16 failure mode can't occur). Per tile:
//   barrier (tile t DMAs landed, all waves)
//   ISSUE(t+1) -> buf[(t+1)&1]   (its readers finished before barrier t)
//   B-prefetch; swizzled ds_read; hi/lo bf16 split; 2x MFMA 32x32x16
// Staging: wave wv DMAs rows 16wv..+15, two 1KB instrs, linear LDS dest,
// source chunk = slot ^ (row&7)  <-> read slot = chunk ^ (row&7) (involution;
// both sides uniform 8 lanes/bank-quad = structural floor).
// No reg staging -> ~55 VGPR -> launch_bounds(256,8): 32 waves/CU.
// kb = bid&7 XCD-locked weights (64KB L2-hot slice). Split-K=8, no atomics.
// ---------------------------------------------------------------------------
__global__ __launch_bounds__(THREADS, 8)
void main_kernel(const float* __restrict__ x,
                 const unsigned short* __restrict__ bwTo,
                 float* __restrict__ pout) {
    __shared__ union {
        float buf[2][64][KT];     // 2 x 8 KB = 16 KB
        float part[2][64][33];    // 16.9 KB k-half combine
    } sm;

    const int tid  = threadIdx.x;
    const int wv   = __builtin_amdgcn_readfirstlane(tid >> 6);
    const int lane = tid & 63;
    const int l31  = lane & 31, lhi = lane >> 5;
    const int kH   = wv & 1;           // k half of tile (16 k)
    const int rH   = wv >> 1;          // row half (32 rows)
    const int kb   = blockIdx.x & 7;   // XCD-locked weight slice
    const int rb   = blockIdx.x >> 3;  // 0..255
    const size_t rowbase = (size_t)rb * 64;
    const int kbase = kb * KSLICE;

    // staging source: instr j covers rows 16wv+8j..+7; lane l -> row offset
    // l>>3, slot l&7 holds global chunk (l&7)^(l>>3)   [row&7 == l>>3]
    const int srow   = lane >> 3;                  // 0..7
    const int schunk = (lane & 7) ^ srow;
    const float* __restrict__ g0 =
        x + (rowbase + 16 * wv + srow) * (size_t)KDIM + kbase + 4 * schunk;
    const float* __restrict__ g1 = g0 + (size_t)8 * KDIM;
    void* const d0a = &sm.buf[0][16 * wv][0];      // linear dests (base + lane*16)
    void* const d0b = &sm.buf[0][16 * wv + 8][0];
    void* const d1a = &sm.buf[1][16 * wv][0];
    void* const d1b = &sm.buf[1][16 * wv + 8][0];

    // B: 8 consecutive bf16 of weight row o=l31 (L2-resident slice)
    const unsigned short* __restrict__ bp =
        bwTo + (size_t)l31 * KDIM + kbase + kH * 16 + lhi * 8;

    // A-read: row = rH*32+l31; logical chunks q0 = kH*4+lhi*2, q0+1 (q0 even)
    const int arow  = rH * 32 + l31;
    const int slot0 = ((kH << 2) | (lhi << 1)) ^ (arow & 7);
    const int slot1 = slot0 ^ 1;

    f32x16 acc;
    #pragma unroll
    for (int i = 0; i < 16; ++i) acc[i] = 0.f;

#define ISSUE(db, t) do {                                        \
        if (db) { gload16(g0 + (t) * KT, d1a);                   \
                  gload16(g1 + (t) * KT, d1b); }                 \
        else    { gload16(g0 + (t) * KT, d0a);                   \
                  gload16(g1 + (t) * KT, d0b); }                 \
    } while (0)

    // prologue: tile 0 -> buf0; b0 in flight
    ISSUE(0, 0);
    bf16x8 bcur = *(const bf16x8*)bp;

    for (int t = 0; t < NTILE; ++t) {
        __syncthreads();   // implicit vmcnt(0) drain: tile t landed, all waves

        if (t + 1 < NTILE) ISSUE((t + 1) & 1, t + 1);   // safe post-barrier
        bf16x8 bnext;
        if (t + 1 < NTILE) bnext = *(const bf16x8*)(bp + (t + 1) * KT);

        const float4 xa = *(const float4*)&sm.buf[t & 1][arow][slot0 * 4];
        const float4 xb = *(const float4*)&sm.buf[t & 1][arow][slot1 * 4];
        bf16x8 ahi, alo;
        {
            const float xf[8] = {xa.x, xa.y, xa.z, xa.w, xb.x, xb.y, xb.z, xb.w};
            #pragma unroll
            for (int j = 0; j < 8; ++j) {
                unsigned bu = __float_as_uint(xf[j]);
                float lo = xf[j] - __uint_as_float(bu & 0xFFFF0000u);   // exact
                ahi[j] = (short)(bu >> 16);
                alo[j] = (short)(__float_as_uint(lo) >> 16);
            }
        }

        acc = __builtin_amdgcn_mfma_f32_32x32x16_bf16(ahi, bcur, acc, 0, 0, 0);
        acc = __builtin_amdgcn_mfma_f32_32x32x16_bf16(alo, bcur, acc, 0, 0, 0);
        bcur = bnext;
    }
#undef ISSUE

    // combine k-halves via LDS, coalesced partial write (R14-proven epilogue)
    __syncthreads();
    #pragma unroll
    for (int r = 0; r < 16; ++r) {
        int row32 = (r & 3) + 8 * (r >> 2) + 4 * lhi;   // C/D layout (m74/m101)
        sm.part[kH][rH * 32 + row32][l31] = acc[r];
    }
    __syncthreads();

    float* __restrict__ pb = pout + ((size_t)kb * BATCH + rowbase) * ODIM;
    #pragma unroll
    for (int i = 0; i < 8; ++i) {
        int j = tid + THREADS * i;        // j = r*32 + o, coalesced
        int r = j >> 5, o = j & 31;
        pb[j] = sm.part[0][r][o] + sm.part[1][r][o];
    }
}

// ---------------------------------------------------------------------------
// Final: recompute scale from |w| partials (deterministic), sum SK partials
// ---------------------------------------------------------------------------
__global__ void reduce_kernel(const float* __restrict__ pout,
                              const float* __restrict__ partial,
                              float* __restrict__ out) {
    const int t = threadIdx.x;
    float a = (partial[t] + partial[t + 256]) + (partial[t + 512] + partial[t + 768]);
    #pragma unroll
    for (int off = 32; off; off >>= 1) a += __shfl_down(a, off, 64);
    __shared__ float red[4];
    __shared__ float sbc;
    if ((t & 63) == 0) red[t >> 6] = a;
    __syncthreads();
    if (t == 0)
        sbc = ((red[0] + red[1]) + (red[2] + red[3])) / (float)(ODIM * KDIM);
    __syncthreads();
    const float s = sbc;

    const int STRIDE = BATCH * ODIM / 4;
    int i = blockIdx.x * 256 + t;
    const float4* p = (const float4*)pout;
    float4 r = p[i];
    #pragma unroll
    for (int k = 1; k < SK; ++k) {
        float4 A = p[i + k * STRIDE];
        r.x += A.x; r.y += A.y; r.z += A.z; r.w += A.w;
    }
    r.x *= s; r.y *= s; r.z *= s; r.w *= s;
    ((float4*)out)[i] = r;
}

// ---------------------------------------------------------------------------
extern "C" void kernel_launch(void* const* d_in, const int* in_sizes, int n_in,
                              void* d_out, int out_size, void* d_ws, size_t ws_size,
                              hipStream_t stream) {
    const float* x = (const float*)d_in[0];
    const float* w = (const float*)d_in[1];
    float* out = (float*)d_out;

    float* wsf = (float*)d_ws;
    float* partial       = wsf;                            // 1024 floats
    unsigned short* bwTo = (unsigned short*)(wsf + 1024);  // 512 KB
    float* pout          = wsf + 1024 + (ODIM * KDIM / 2); // SK*2MB = 16 MB

    prep_kernel<<<1024, 256, 0, stream>>>(w, bwTo, partial);
    main_kernel<<<256 * SK, THREADS, 0, stream>>>(x, bwTo, pout);
    reduce_kernel<<<BATCH * ODIM / 4 / 256, 256, 0, stream>>>(pout, partial, out);
}

// Round 18
// 126.547 us; speedup vs baseline: 1.4372x; 1.1225x over previous
//
#include <hip/hip_runtime.h>

#define BATCH 16384
#define KDIM  8192
#define ODIM  32
#define SK    8
#define KSLICE (KDIM / SK)       // 1024 k per block
#define KHALF  (KSLICE / 2)      // 512 k per wave
#define KT    32                 // k per wave-tile
#define NT    (KHALF / KT)       // 16 tiles
#define THREADS 256

typedef short bf16x8 __attribute__((ext_vector_type(8)));
typedef float f32x16 __attribute__((ext_vector_type(16)));

// ---------------------------------------------------------------------------
// Prep: bwTo[o][k] = sign(w[o][k]) as bf16 (+-1.0 exact / 0), + |w| partials
// ---------------------------------------------------------------------------
__global__ void prep_kernel(const float* __restrict__ w,
                            unsigned short* __restrict__ bwTo,
                            float* __restrict__ partial) {
    int idx = blockIdx.x * 256 + threadIdx.x;     // = o*8192 + k, coalesced
    float v = w[idx];
    bwTo[idx] = (v > 0.f) ? 0x3F80u : ((v < 0.f) ? 0xBF80u : 0u);

    float a = fabsf(v);
    #pragma unroll
    for (int off = 32; off; off >>= 1) a += __shfl_down(a, off, 64);
    __shared__ float red[4];
    int lane = threadIdx.x & 63, wv = threadIdx.x >> 6;
    if (lane == 0) red[wv] = a;
    __syncthreads();
    if (threadIdx.x == 0)
        partial[blockIdx.x] = (red[0] + red[1]) + (red[2] + red[3]);
}

// ---------------------------------------------------------------------------
// Main: ZERO barriers in the K-loop. Wave-private double-buffered LDS tile
// (32 rows x 32 k) staged via regs + ds_write — every dependence is visible
// to the compiler (global->reg vmcnt, reg->ds_write, ds_write->ds_read lgkm,
// ->MFMA), so waits are compiler-exact: correctness by construction, and no
// block-wide vmcnt(0) drain (R14/R17's limiter — blocks could never hold
// more than one tile in flight). Waves drift freely; HBM queue stays fed.
// Staging: 4 x 1KB loads (8 rows x 128B each, full coalescing); LDS write
// slot = chunk ^ (row&7), read undoes it (8 lanes/bank-quad = floor).
// wave = (rH rows-half, kH k-half); kb = bid&7 XCD-locked weights (L2-hot).
// Split-K=8 partials, deterministic, no atomics.
// ---------------------------------------------------------------------------
__global__ __launch_bounds__(THREADS, 6)
void main_kernel(const float* __restrict__ x,
                 const unsigned short* __restrict__ bwTo,
                 float* __restrict__ pout) {
    __shared__ union {
        float buf[4][2][32][KT];  // [wave][db][row][32f] = 32 KB
        float part[2][64][33];    // 16.9 KB k-half combine
    } sm;

    const int tid  = threadIdx.x;
    const int wv   = __builtin_amdgcn_readfirstlane(tid >> 6);
    const int lane = tid & 63;
    const int l31  = lane & 31, lhi = lane >> 5;
    const int kH   = wv & 1;           // k half (512 k)
    const int rH   = wv >> 1;          // row half (32 rows)
    const int kb   = blockIdx.x & 7;   // XCD-locked weight slice
    const int rb   = blockIdx.x >> 3;  // 0..255
    const size_t rowbase = (size_t)rb * 64;
    const int kbase = kb * KSLICE + kH * KHALF;

    // staging: instr j covers rows rH*32 + 8j + (l>>3); lane chunk c = l&7
    const int srow8 = lane >> 3;               // 0..7
    const int sc    = lane & 7;                // global chunk (linear, coalesced)
    const int ssl   = sc ^ srow8;              // LDS slot (write-side swizzle)
    const float* __restrict__ g0 =
        x + (rowbase + rH * 32 + srow8) * (size_t)KDIM + kbase + 4 * sc;
    const float* __restrict__ g1 = g0 + (size_t)8  * KDIM;
    const float* __restrict__ g2 = g0 + (size_t)16 * KDIM;
    const float* __restrict__ g3 = g0 + (size_t)24 * KDIM;

    // B: 8 consecutive bf16 of weight row o=l31 (L2-resident 64KB slice)
    const unsigned short* __restrict__ bp =
        bwTo + (size_t)l31 * KDIM + kbase + lhi * 8;

    // A-read float offsets within row l31: step s, chunks q=4s+2*lhi, +1
    const int m7 = l31 & 7;
    const int ro00 = 4 * ((0 + 2 * lhi) ^ m7);   // s=0, first
    const int ro01 = 4 * ((1 + 2 * lhi) ^ m7);   // s=0, second
    const int ro10 = 4 * ((4 + 2 * lhi) ^ m7);   // s=1, first
    const int ro11 = 4 * ((5 + 2 * lhi) ^ m7);   // s=1, second
    const float* const rb0 = &sm.buf[wv][0][l31][0];
    const float* const rb1 = &sm.buf[wv][1][l31][0];

    f32x16 acc;
    #pragma unroll
    for (int i = 0; i < 16; ++i) acc[i] = 0.f;

    float4 st0, st1, st2, st3;
#define LOADT(t) do {                               \
        st0 = *(const float4*)(g0 + (t) * KT);      \
        st1 = *(const float4*)(g1 + (t) * KT);      \
        st2 = *(const float4*)(g2 + (t) * KT);      \
        st3 = *(const float4*)(g3 + (t) * KT);      \
    } while (0)
#define WRITET(db) do {                                         \
        *(float4*)&sm.buf[wv][db][srow8     ][4 * ssl] = st0;   \
        *(float4*)&sm.buf[wv][db][srow8 +  8][4 * ssl] = st1;   \
        *(float4*)&sm.buf[wv][db][srow8 + 16][4 * ssl] = st2;   \
        *(float4*)&sm.buf[wv][db][srow8 + 24][4 * ssl] = st3;   \
    } while (0)

    bf16x8 ahi, alo;
#define STEP(base, o0, o1, bfr) do {                                      \
        const float4 xa = *(const float4*)((base) + (o0));                \
        const float4 xb = *(const float4*)((base) + (o1));                \
        const float xf[8] = {xa.x, xa.y, xa.z, xa.w,                      \
                             xb.x, xb.y, xb.z, xb.w};                     \
        _Pragma("unroll")                                                 \
        for (int j = 0; j < 8; ++j) {                                     \
            unsigned bu = __float_as_uint(xf[j]);                         \
            float lo = xf[j] - __uint_as_float(bu & 0xFFFF0000u);         \
            ahi[j] = (short)(bu >> 16);                                   \
            alo[j] = (short)(__float_as_uint(lo) >> 16);                  \
        }                                                                 \
        acc = __builtin_amdgcn_mfma_f32_32x32x16_bf16(ahi, bfr, acc, 0, 0, 0); \
        acc = __builtin_amdgcn_mfma_f32_32x32x16_bf16(alo, bfr, acc, 0, 0, 0); \
    } while (0)

    // prologue: tile 0 staged to buf0; tile 1 in regs; B(0) in flight
    LOADT(0);
    WRITET(0);
    LOADT(1);
    bf16x8 b0 = *(const bf16x8*)(bp);
    bf16x8 b1 = *(const bf16x8*)(bp + 16);

    for (int t = 0; t < NT; ++t) {
        const int db = t & 1;
        const float* base = db ? rb1 : rb0;

        STEP(base, ro00, ro01, b0);                 // k-step 0 of tile t

        bf16x8 bn0, bn1;
        if (t + 1 < NT) {                           // prefetch next tile's B
            bn0 = *(const bf16x8*)(bp + (t + 1) * KT);
            bn1 = *(const bf16x8*)(bp + (t + 1) * KT + 16);
        }

        STEP(base, ro10, ro11, b1);                 // k-step 1 of tile t

        if (t + 1 < NT) WRITET(db ^ 1);             // stage tile t+1 (regs->LDS)
        if (t + 2 < NT) LOADT(t + 2);               // reuse regs after ds_write
        b0 = bn0; b1 = bn1;
    }
#undef LOADT
#undef WRITET
#undef STEP

    // combine k-halves via LDS (only barriers in the kernel)
    __syncthreads();
    #pragma unroll
    for (int r = 0; r < 16; ++r) {
        int row32 = (r & 3) + 8 * (r >> 2) + 4 * lhi;   // C/D layout (m74/m101)
        sm.part[kH][rH * 32 + row32][l31] = acc[r];
    }
    __syncthreads();

    float* __restrict__ pb = pout + ((size_t)kb * BATCH + rowbase) * ODIM;
    #pragma unroll
    for (int i = 0; i < 8; ++i) {
        int j = tid + THREADS * i;        // j = r*32 + o, coalesced
        int r = j >> 5, o = j & 31;
        pb[j] = sm.part[0][r][o] + sm.part[1][r][o];
    }
}

// ---------------------------------------------------------------------------
// Final: recompute scale from |w| partials (deterministic), sum SK partials
// ---------------------------------------------------------------------------
__global__ void reduce_kernel(const float* __restrict__ pout,
                              const float* __restrict__ partial,
                              float* __restrict__ out) {
    const int t = threadIdx.x;
    float a = (partial[t] + partial[t + 256]) + (partial[t + 512] + partial[t + 768]);
    #pragma unroll
    for (int off = 32; off; off >>= 1) a += __shfl_down(a, off, 64);
    __shared__ float red[4];
    __shared__ float sbc;
    if ((t & 63) == 0) red[t >> 6] = a;
    __syncthreads();
    if (t == 0)
        sbc = ((red[0] + red[1]) + (red[2] + red[3])) / (float)(ODIM * KDIM);
    __syncthreads();
    const float s = sbc;

    const int STRIDE = BATCH * ODIM / 4;
    int i = blockIdx.x * 256 + t;
    const float4* p = (const float4*)pout;
    float4 r = p[i];
    #pragma unroll
    for (int k = 1; k < SK; ++k) {
        float4 A = p[i + k * STRIDE];
        r.x += A.x; r.y += A.y; r.z += A.z; r.w += A.w;
    }
    r.x *= s; r.y *= s; r.z *= s; r.w *= s;
    ((float4*)out)[i] = r;
}

// ---------------------------------------------------------------------------
extern "C" void kernel_launch(void* const* d_in, const int* in_sizes, int n_in,
                              void* d_out, int out_size, void* d_ws, size_t ws_size,
                              hipStream_t stream) {
    const float* x = (const float*)d_in[0];
    const float* w = (const float*)d_in[1];
    float* out = (float*)d_out;

    float* wsf = (float*)d_ws;
    float* partial       = wsf;                            // 1024 floats
    unsigned short* bwTo = (unsigned short*)(wsf + 1024);  // 512 KB
    float* pout          = wsf + 1024 + (ODIM * KDIM / 2); // SK*2MB = 16 MB

    prep_kernel<<<1024, 256, 0, stream>>>(w, bwTo, partial);
    main_kernel<<<256 * SK, THREADS, 0, stream>>>(x, bwTo, pout);
    reduce_kernel<<<BATCH * ODIM / 4 / 256, 256, 0, stream>>>(pout, partial, out);
}

// Round 19
// 126.511 us; speedup vs baseline: 1.4376x; 1.0003x over previous
//
#include <hip/hip_runtime.h>

#define BATCH 16384
#define KDIM  8192
#define ODIM  32
#define SK    8
#define KSLICE (KDIM / SK)       // 1024 k per block
#define KHALF  (KSLICE / 2)      // 512 k per wave
#define KT    64                 // k per wave-tile (256 B per row -> long bursts)
#define NT    (KHALF / KT)       // 8 tiles
#define THREADS 256

typedef short bf16x8 __attribute__((ext_vector_type(8)));
typedef float f32x16 __attribute__((ext_vector_type(16)));

__device__ __forceinline__ uint2 pack_bf16rn(float4 v) {
    unsigned b0 = __float_as_uint(v.x), b1 = __float_as_uint(v.y);
    unsigned b2 = __float_as_uint(v.z), b3 = __float_as_uint(v.w);
    uint2 r;
    r.x = ((b0 + 0x8000u) >> 16) | ((b1 + 0x8000u) & 0xFFFF0000u);
    r.y = ((b2 + 0x8000u) >> 16) | ((b3 + 0x8000u) & 0xFFFF0000u);
    return r;
}

// ---------------------------------------------------------------------------
// Prep: bwTo[o][k] = sign(w[o][k]) as bf16 (+-1.0 exact / 0), + |w| partials
// ---------------------------------------------------------------------------
__global__ void prep_kernel(const float* __restrict__ w,
                            unsigned short* __restrict__ bwTo,
                            float* __restrict__ partial) {
    int idx = blockIdx.x * 256 + threadIdx.x;     // = o*8192 + k, coalesced
    float v = w[idx];
    bwTo[idx] = (v > 0.f) ? 0x3F80u : ((v < 0.f) ? 0xBF80u : 0u);

    float a = fabsf(v);
    #pragma unroll
    for (int off = 32; off; off >>= 1) a += __shfl_down(a, off, 64);
    __shared__ float red[4];
    int lane = threadIdx.x & 63, wv = threadIdx.x >> 6;
    if (lane == 0) red[wv] = a;
    __syncthreads();
    if (threadIdx.x == 0)
        partial[blockIdx.x] = (red[0] + red[1]) + (red[2] + red[3]);
}

// ---------------------------------------------------------------------------
// Main: zero-barrier wave-private pipeline (R18-proven), restructured for
// 256 B-per-row load instructions (4 rows x 16 lanes x 16B), k-tile = 64.
// x staged as SINGLE bf16 (RTN pack) -> 4 KB/tile, dbuf 8 KB/wave, 32 KB/blk
// = 5 blocks/CU (20 waves). 1 MFMA per k-16 step (4/tile). All dependences
// compiler-visible (reg staging + ds_write/ds_read) -> exact waits, no
// counted-vmcnt, no block barriers in the K-loop.
// LDS swizzle: 16B slot = (chunk>>1) ^ (row&7) both sides (involution);
// write uniform 4 dwords/bank, read uniform 8/bank = structural floors.
// kb = bid&7 XCD-locked weights (64KB L2-hot slice). Split-K=8, no atomics.
// ---------------------------------------------------------------------------
__global__ __launch_bounds__(THREADS, 5)
void main_kernel(const float* __restrict__ x,
                 const unsigned short* __restrict__ bwTo,
                 float* __restrict__ pout) {
    __shared__ union {
        unsigned short buf[4][2][32][KT];  // [wave][db][row][64 bf16] = 32 KB
        float part[2][64][33];             // 16.9 KB k-half combine
    } sm;

    const int tid  = threadIdx.x;
    const int wv   = __builtin_amdgcn_readfirstlane(tid >> 6);
    const int lane = tid & 63;
    const int l31  = lane & 31, lhi = lane >> 5;
    const int m7   = l31 & 7;
    const int kH   = wv & 1;           // k half (512 k)
    const int rH   = wv >> 1;          // row half (32 rows)
    const int kb   = blockIdx.x & 7;   // XCD-locked weight slice
    const int rb   = blockIdx.x >> 3;  // 0..255
    const size_t rowbase = (size_t)rb * 64;
    const int kbase = kb * KSLICE + kH * KHALF;

    // staging: load j covers rows rH*32 + 4j + srow4; lane chunk sc (16B)
    const int srow4 = lane >> 4;               // 0..3
    const int sc    = lane & 15;               // 0..15 (256 B per row)
    const float* __restrict__ gb =
        x + (rowbase + rH * 32 + srow4) * (size_t)KDIM + kbase + 4 * sc;

    // LDS write offsets (ushort units): row 4j+srow4, slot=(sc>>1)^(row&7)
    const int chE = (((sc >> 1) ^ srow4) << 3) + (sc & 1) * 4;   // j even
    const int chO = chE ^ 32;                                    // j odd

    // B: 8 consecutive bf16 of weight row o=l31 (L2-resident 64KB slice)
    const unsigned short* __restrict__ bp =
        bwTo + (size_t)l31 * KDIM + kbase + lhi * 8;

    // A-read offsets (ushort units): row l31, step s: slot=(2s+lhi)^m7
    const int ro0 = l31 * 64 + (((0 + lhi) ^ m7) << 3);
    const int ro1 = l31 * 64 + (((2 + lhi) ^ m7) << 3);
    const int ro2 = l31 * 64 + (((4 + lhi) ^ m7) << 3);
    const int ro3 = l31 * 64 + (((6 + lhi) ^ m7) << 3);
    const unsigned short* const rbA = &sm.buf[wv][0][0][0];
    const unsigned short* const rbB = &sm.buf[wv][1][0][0];

    f32x16 acc;
    #pragma unroll
    for (int i = 0; i < 16; ++i) acc[i] = 0.f;

    uint2 pk0, pk1, pk2, pk3, pk4, pk5, pk6, pk7;

#define LOADPACK(t) do {                                                      \
        float4 s0 = *(const float4*)(gb + (size_t) 0 * KDIM + (t) * KT);      \
        float4 s1 = *(const float4*)(gb + (size_t) 4 * KDIM + (t) * KT);      \
        float4 s2 = *(const float4*)(gb + (size_t) 8 * KDIM + (t) * KT);      \
        float4 s3 = *(const float4*)(gb + (size_t)12 * KDIM + (t) * KT);      \
        pk0 = pack_bf16rn(s0); pk1 = pack_bf16rn(s1);                         \
        pk2 = pack_bf16rn(s2); pk3 = pack_bf16rn(s3);                         \
        float4 s4 = *(const float4*)(gb + (size_t)16 * KDIM + (t) * KT);      \
        float4 s5 = *(const float4*)(gb + (size_t)20 * KDIM + (t) * KT);      \
        float4 s6 = *(const float4*)(gb + (size_t)24 * KDIM + (t) * KT);      \
        float4 s7 = *(const float4*)(gb + (size_t)28 * KDIM + (t) * KT);      \
        pk4 = pack_bf16rn(s4); pk5 = pack_bf16rn(s5);                         \
        pk6 = pack_bf16rn(s6); pk7 = pack_bf16rn(s7);                         \
    } while (0)

#define WRITET(db) do {                                                       \
        *(uint2*)&sm.buf[wv][db][ 0 + srow4][chE] = pk0;                      \
        *(uint2*)&sm.buf[wv][db][ 4 + srow4][chO] = pk1;                      \
        *(uint2*)&sm.buf[wv][db][ 8 + srow4][chE] = pk2;                      \
        *(uint2*)&sm.buf[wv][db][12 + srow4][chO] = pk3;                      \
        *(uint2*)&sm.buf[wv][db][16 + srow4][chE] = pk4;                      \
        *(uint2*)&sm.buf[wv][db][20 + srow4][chO] = pk5;                      \
        *(uint2*)&sm.buf[wv][db][24 + srow4][chE] = pk6;                      \
        *(uint2*)&sm.buf[wv][db][28 + srow4][chO] = pk7;                      \
    } while (0)

#define STEP(base, ro, boff) do {                                             \
        bf16x8 av = *(const bf16x8*)((base) + (ro));                          \
        bf16x8 bv = *(const bf16x8*)(bp + (boff));                            \
        acc = __builtin_amdgcn_mfma_f32_32x32x16_bf16(av, bv, acc, 0, 0, 0);  \
    } while (0)

    // prologue: tile 0 staged; tile 1 packed in regs
    LOADPACK(0);
    WRITET(0);
    LOADPACK(1);

    for (int t = 0; t < NT; ++t) {
        const unsigned short* base = (t & 1) ? rbB : rbA;
        const int tb = t * KT;                 // B bf16 offset of tile t
        STEP(base, ro0, tb);
        STEP(base, ro1, tb + 16);
        STEP(base, ro2, tb + 32);
        STEP(base, ro3, tb + 48);
        if (t + 1 < NT) WRITET((t + 1) & 1);   // stage tile t+1 (pk -> LDS)
        if (t + 2 < NT) LOADPACK(t + 2);       // refill pk (regs free post-write)
    }
#undef LOADPACK
#undef WRITET
#undef STEP

    // combine k-halves via LDS (only barriers in the kernel)
    __syncthreads();
    #pragma unroll
    for (int r = 0; r < 16; ++r) {
        int row32 = (r & 3) + 8 * (r >> 2) + 4 * lhi;   // C/D layout (m74/m101)
        sm.part[kH][rH * 32 + row32][l31] = acc[r];
    }
    __syncthreads();

    float* __restrict__ pb = pout + ((size_t)kb * BATCH + rowbase) * ODIM;
    #pragma unroll
    for (int i = 0; i < 8; ++i) {
        int j = tid + THREADS * i;        // j = r*32 + o, coalesced
        int r = j >> 5, o = j & 31;
        pb[j] = sm.part[0][r][o] + sm.part[1][r][o];
    }
}

// ---------------------------------------------------------------------------
// Final: recompute scale from |w| partials (deterministic), sum SK partials
// ---------------------------------------------------------------------------
__global__ void reduce_kernel(const float* __restrict__ pout,
                              const float* __restrict__ partial,
                              float* __restrict__ out) {
    const int t = threadIdx.x;
    float a = (partial[t] + partial[t + 256]) + (partial[t + 512] + partial[t + 768]);
    #pragma unroll
    for (int off = 32; off; off >>= 1) a += __shfl_down(a, off, 64);
    __shared__ float red[4];
    __shared__ float sbc;
    if ((t & 63) == 0) red[t >> 6] = a;
    __syncthreads();
    if (t == 0)
        sbc = ((red[0] + red[1]) + (red[2] + red[3])) / (float)(ODIM * KDIM);
    __syncthreads();
    const float s = sbc;

    const int STRIDE = BATCH * ODIM / 4;
    int i = blockIdx.x * 256 + t;
    const float4* p = (const float4*)pout;
    float4 r = p[i];
    #pragma unroll
    for (int k = 1; k < SK; ++k) {
        float4 A = p[i + k * STRIDE];
        r.x += A.x; r.y += A.y; r.z += A.z; r.w += A.w;
    }
    r.x *= s; r.y *= s; r.z *= s; r.w *= s;
    ((float4*)out)[i] = r;
}

// ---------------------------------------------------------------------------
extern "C" void kernel_launch(void* const* d_in, const int* in_sizes, int n_in,
                              void* d_out, int out_size, void* d_ws, size_t ws_size,
                              hipStream_t stream) {
    const float* x = (const float*)d_in[0];
    const float* w = (const float*)d_in[1];
    float* out = (float*)d_out;

    float* wsf = (float*)d_ws;
    float* partial       = wsf;                            // 1024 floats
    unsigned short* bwTo = (unsigned short*)(wsf + 1024);  // 512 KB
    float* pout          = wsf + 1024 + (ODIM * KDIM / 2); // SK*2MB = 16 MB

    prep_kernel<<<1024, 256, 0, stream>>>(w, bwTo, partial);
    main_kernel<<<256 * SK, THREADS, 0, stream>>>(x, bwTo, pout);
    reduce_kernel<<<BATCH * ODIM / 4 / 256, 256, 0, stream>>>(pout, partial, out);
}

// Round 20
// 120.422 us; speedup vs baseline: 1.5103x; 1.0506x over previous
//
#include <hip/hip_runtime.h>

#define BATCH 16384
#define KDIM  8192
#define ODIM  32
#define SK    8
#define KSLICE (KDIM / SK)       // 1024 k per block
#define KHALF  (KSLICE / 2)      // 512 k per wave
#define KT    32                 // k per wave-tile (128 B per row bursts)
#define NT    (KHALF / KT)       // 16 tiles
#define THREADS 256

typedef short bf16x8 __attribute__((ext_vector_type(8)));
typedef float f32x16 __attribute__((ext_vector_type(16)));

__device__ __forceinline__ uint2 pack_bf16rn(float4 v) {
    unsigned b0 = __float_as_uint(v.x), b1 = __float_as_uint(v.y);
    unsigned b2 = __float_as_uint(v.z), b3 = __float_as_uint(v.w);
    uint2 r;
    r.x = ((b0 + 0x8000u) >> 16) | ((b1 + 0x8000u) & 0xFFFF0000u);
    r.y = ((b2 + 0x8000u) >> 16) | ((b3 + 0x8000u) & 0xFFFF0000u);
    return r;
}

// ---------------------------------------------------------------------------
// Prep: bwTo[o][k] = sign(w[o][k]) as bf16 (+-1.0 exact / 0), + |w| partials
// ---------------------------------------------------------------------------
__global__ void prep_kernel(const float* __restrict__ w,
                            unsigned short* __restrict__ bwTo,
                            float* __restrict__ partial) {
    int idx = blockIdx.x * 256 + threadIdx.x;     // = o*8192 + k, coalesced
    float v = w[idx];
    bwTo[idx] = (v > 0.f) ? 0x3F80u : ((v < 0.f) ? 0xBF80u : 0u);

    float a = fabsf(v);
    #pragma unroll
    for (int off = 32; off; off >>= 1) a += __shfl_down(a, off, 64);
    __shared__ float red[4];
    int lane = threadIdx.x & 63, wv = threadIdx.x >> 6;
    if (lane == 0) red[wv] = a;
    __syncthreads();
    if (threadIdx.x == 0)
        partial[blockIdx.x] = (red[0] + red[1]) + (red[2] + red[3]);
}

// ---------------------------------------------------------------------------
// Main: R18/R19 zero-barrier wave-private pipeline at 32 waves/CU.
// KT=32 + bf16 LDS staging -> 16.4 KB/block -> 8 blocks/CU (the one untested
// streaming axis: occupancy 20 -> 32 w/CU for more outstanding HBM reqs).
// Staging: 4 loads x (8 rows x 128 B), pack RTN bf16, ds_write_b64 swizzled
// slot = 2*((sc>>1)^((row>>1)&3)) + (sc&1); read pair g^((row>>1)&3) undoes
// it (write 4 dwords/bank, read 8/bank = structural floors). All deps
// compiler-visible; no counted vmcnt, no block barriers in K-loop.
// kb = bid&7 XCD-locked weights (L2-hot). Split-K=8 partials, no atomics.
// ---------------------------------------------------------------------------
__global__ __launch_bounds__(THREADS, 8)
void main_kernel(const float* __restrict__ x,
                 const unsigned short* __restrict__ bwTo,
                 float* __restrict__ pout) {
    __shared__ union {
        unsigned short buf[4][2][32][KT];  // [wave][db][row][32 bf16] = 16 KB
        float part[2][64][33];             // 16.9 KB k-half combine
    } sm;

    const int tid  = threadIdx.x;
    const int wv   = __builtin_amdgcn_readfirstlane(tid >> 6);
    const int lane = tid & 63;
    const int l31  = lane & 31, lhi = lane >> 5;
    const int kH   = wv & 1;           // k half (512 k)
    const int rH   = wv >> 1;          // row half (32 rows)
    const int kb   = blockIdx.x & 7;   // XCD-locked weight slice
    const int rb   = blockIdx.x >> 3;  // 0..255
    const size_t rowbase = (size_t)rb * 64;
    const int kbase = kb * KSLICE + kH * KHALF;

    // staging: load j covers rows rH*32 + 8j + srow8; sc = 16B fp32 chunk
    const int srow8 = lane >> 3;               // 0..7
    const int sc    = lane & 7;                // 0..7 (128 B per row)
    const float* __restrict__ g0 =
        x + (rowbase + rH * 32 + srow8) * (size_t)KDIM + kbase + 4 * sc;
    const float* __restrict__ g1 = g0 + (size_t)8  * KDIM;
    const float* __restrict__ g2 = g0 + (size_t)16 * KDIM;
    const float* __restrict__ g3 = g0 + (size_t)24 * KDIM;

    // LDS write offset (ushort units): slot independent of j (8j>>1 ≡ 0 mod 4)
    const int wslot = (2 * ((sc >> 1) ^ ((srow8 >> 1) & 3)) + (sc & 1)) * 4;

    // B: 8 consecutive bf16 of weight row o=l31 (L2-resident 64KB slice)
    const unsigned short* __restrict__ bp =
        bwTo + (size_t)l31 * KDIM + kbase + lhi * 8;

    // A-read offsets (ushort units): row l31, step s: pair (2s|lhi)^pr
    const int pr  = (l31 >> 1) & 3;
    const int ro0 = l31 * KT + ((lhi    ) ^ pr) * 8;
    const int ro1 = l31 * KT + ((2 | lhi) ^ pr) * 8;
    const unsigned short* const rbA = &sm.buf[wv][0][0][0];
    const unsigned short* const rbB = &sm.buf[wv][1][0][0];

    f32x16 acc;
    #pragma unroll
    for (int i = 0; i < 16; ++i) acc[i] = 0.f;

    uint2 pk0, pk1, pk2, pk3;

#define LOADPACK(t) do {                                                      \
        float4 s0 = *(const float4*)(g0 + (t) * KT);                          \
        float4 s1 = *(const float4*)(g1 + (t) * KT);                          \
        float4 s2 = *(const float4*)(g2 + (t) * KT);                          \
        float4 s3 = *(const float4*)(g3 + (t) * KT);                          \
        pk0 = pack_bf16rn(s0); pk1 = pack_bf16rn(s1);                         \
        pk2 = pack_bf16rn(s2); pk3 = pack_bf16rn(s3);                         \
    } while (0)

#define WRITET(db) do {                                                       \
        *(uint2*)&sm.buf[wv][db][ 0 + srow8][wslot] = pk0;                    \
        *(uint2*)&sm.buf[wv][db][ 8 + srow8][wslot] = pk1;                    \
        *(uint2*)&sm.buf[wv][db][16 + srow8][wslot] = pk2;                    \
        *(uint2*)&sm.buf[wv][db][24 + srow8][wslot] = pk3;                    \
    } while (0)

#define STEP(base, ro, boff) do {                                             \
        bf16x8 av = *(const bf16x8*)((base) + (ro));                          \
        bf16x8 bv = *(const bf16x8*)(bp + (boff));                            \
        acc = __builtin_amdgcn_mfma_f32_32x32x16_bf16(av, bv, acc, 0, 0, 0);  \
    } while (0)

    // prologue: tile 0 staged; tile 1 packed in regs
    LOADPACK(0);
    WRITET(0);
    LOADPACK(1);

    for (int t = 0; t < NT; ++t) {
        const unsigned short* base = (t & 1) ? rbB : rbA;
        STEP(base, ro0, t * KT);           // k-step 0 (K=16)
        STEP(base, ro1, t * KT + 16);      // k-step 1
        if (t + 1 < NT) WRITET((t + 1) & 1);   // stage tile t+1 (pk -> LDS)
        if (t + 2 < NT) LOADPACK(t + 2);       // refill pk (regs free post-write)
    }
#undef LOADPACK
#undef WRITET
#undef STEP

    // combine k-halves via LDS (only barriers in the kernel)
    __syncthreads();
    #pragma unroll
    for (int r = 0; r < 16; ++r) {
        int row32 = (r & 3) + 8 * (r >> 2) + 4 * lhi;   // C/D layout (m74/m101)
        sm.part[kH][rH * 32 + row32][l31] = acc[r];
    }
    __syncthreads();

    float* __restrict__ pb = pout + ((size_t)kb * BATCH + rowbase) * ODIM;
    #pragma unroll
    for (int i = 0; i < 8; ++i) {
        int j = tid + THREADS * i;        // j = r*32 + o, coalesced
        int r = j >> 5, o = j & 31;
        pb[j] = sm.part[0][r][o] + sm.part[1][r][o];
    }
}

// ---------------------------------------------------------------------------
// Final: recompute scale from |w| partials (deterministic), sum SK partials
// ---------------------------------------------------------------------------
__global__ void reduce_kernel(const float* __restrict__ pout,
                              const float* __restrict__ partial,
                              float* __restrict__ out) {
    const int t = threadIdx.x;
    float a = (partial[t] + partial[t + 256]) + (partial[t + 512] + partial[t + 768]);
    #pragma unroll
    for (int off = 32; off; off >>= 1) a += __shfl_down(a, off, 64);
    __shared__ float red[4];
    __shared__ float sbc;
    if ((t & 63) == 0) red[t >> 6] = a;
    __syncthreads();
    if (t == 0)
        sbc = ((red[0] + red[1]) + (red[2] + red[3])) / (float)(ODIM * KDIM);
    __syncthreads();
    const float s = sbc;

    const int STRIDE = BATCH * ODIM / 4;
    int i = blockIdx.x * 256 + t;
    const float4* p = (const float4*)pout;
    float4 r = p[i];
    #pragma unroll
    for (int k = 1; k < SK; ++k) {
        float4 A = p[i + k * STRIDE];
        r.x += A.x; r.y += A.y; r.z += A.z; r.w += A.w;
    }
    r.x *= s; r.y *= s; r.z *= s; r.w *= s;
    ((float4*)out)[i] = r;
}

// ---------------------------------------------------------------------------
extern "C" void kernel_launch(void* const* d_in, const int* in_sizes, int n_in,
                              void* d_out, int out_size, void* d_ws, size_t ws_size,
                              hipStream_t stream) {
    const float* x = (const float*)d_in[0];
    const float* w = (const float*)d_in[1];
    float* out = (float*)d_out;

    float* wsf = (float*)d_ws;
    float* partial       = wsf;                            // 1024 floats
    unsigned short* bwTo = (unsigned short*)(wsf + 1024);  // 512 KB
    float* pout          = wsf + 1024 + (ODIM * KDIM / 2); // SK*2MB = 16 MB

    prep_kernel<<<1024, 256, 0, stream>>>(w, bwTo, partial);
    main_kernel<<<256 * SK, THREADS, 0, stream>>>(x, bwTo, pout);
    reduce_kernel<<<BATCH * ODIM / 4 / 256, 256, 0, stream>>>(pout, partial, out);
}